// Round 7
// baseline (27.533 us; speedup 1.0000x reference)
//
#include <hip/hip_runtime.h>

// ROI max-pool: [512*256 planes, 14x14] fp32 -> [planes, 7x7] fp32.
// Exact 2x2 non-overlapping max windows. Memory-bound (~103 MB in, ~26 MB out).
//
// R7: R5 structure (best so far, 24.35us) + NONTEMPORAL LOADS on the staging
// reads. Input is strictly streaming (read once; harness fills evict L3
// between replays) -- NT reads skip L2/L3 allocation, leaving L2 free for
// output write-combining. Writes stay cached (R4 proved NT stores regress).

typedef float f32x4 __attribute__((ext_vector_type(4)));

#define PPB   16          // planes per block
#define BLOCK 256

__global__ __launch_bounds__(BLOCK)
void ROIPooling_86466281603470_kernel(const float* __restrict__ in,
                                      float* __restrict__ out) {
    __shared__ float lds[PPB * 196];   // 12544 B

    const int pb = blockIdx.x * PPB;   // first plane handled by this block

    // ---- stage: 16 planes = 784 x 16B, perfectly coalesced, NT reads ----
    const f32x4* __restrict__ in4 =
        reinterpret_cast<const f32x4*>(in + (size_t)pb * 196);
    f32x4* lds4 = reinterpret_cast<f32x4*>(lds);
    #pragma unroll
    for (int v = threadIdx.x; v < PPB * 49; v += BLOCK) {
        lds4[v] = __builtin_nontemporal_load(&in4[v]);
    }
    __syncthreads();

    // ---- compute: 784 outputs = 196 x 16B regular stores ----
    f32x4* __restrict__ out4 =
        reinterpret_cast<f32x4*>(out + (size_t)pb * 49);  // 3136 B aligned
    const int t = threadIdx.x;
    if (t < PPB * 49 / 4) {            // 196 active threads
        f32x4 r;
        #pragma unroll
        for (int q = 0; q < 4; ++q) {
            int o   = 4 * t + q;
            int p   = o / 49;          // plane within block (magic-mul)
            int rem = o - p * 49;
            int i   = rem / 7;         // output row
            int j   = rem - i * 7;     // output col
            const float* base = lds + p * 196 + i * 28 + 2 * j;
            float2 a = *reinterpret_cast<const float2*>(base);        // row 2i
            float2 b = *reinterpret_cast<const float2*>(base + 14);   // row 2i+1
            r[q] = fmaxf(fmaxf(a.x, a.y), fmaxf(b.x, b.y));
        }
        out4[t] = r;
    }
}

extern "C" void kernel_launch(void* const* d_in, const int* in_sizes, int n_in,
                              void* d_out, int out_size, void* d_ws, size_t ws_size,
                              hipStream_t stream) {
    const float* in = (const float*)d_in[0];
    float* out = (float*)d_out;
    int n_planes = out_size / 49;            // 512*256 = 131072, divisible by PPB
    int grid = n_planes / PPB;               // 8192 blocks
    ROIPooling_86466281603470_kernel<<<grid, BLOCK, 0, stream>>>(in, out);
}

// Round 8
// 24.258 us; speedup vs baseline: 1.1350x; 1.1350x over previous
//
#include <hip/hip_runtime.h>

// ROI max-pool: [512*256 planes, 14x14] fp32 -> [planes, 7x7] fp32.
// Exact 2x2 non-overlapping max windows. Memory-bound (~103 MB in, ~26 MB out).
//
// R8: R5 structure (best, 24.35us; 16B cached loads+stores, LDS staging) with
// DOUBLE the per-block work: PPB=32, BLOCK=512. Same 32 waves/CU occupancy
// (25 KB LDS -> 4 blocks/CU x 8 waves), half the dispatch count (4096 blocks)
// -- isolates block launch/retire granularity, the one untested parameter.
// NT hints on either stream regress (R4, R7): keep everything cached.

typedef float f32x4 __attribute__((ext_vector_type(4)));

#define PPB   32          // planes per block
#define BLOCK 512

__global__ __launch_bounds__(BLOCK)
void ROIPooling_86466281603470_kernel(const float* __restrict__ in,
                                      float* __restrict__ out) {
    __shared__ float lds[PPB * 196];   // 25088 B

    const int pb = blockIdx.x * PPB;   // first plane handled by this block

    // ---- stage: 32 planes = 1568 x 16B, perfectly coalesced ----
    const f32x4* __restrict__ in4 =
        reinterpret_cast<const f32x4*>(in + (size_t)pb * 196);
    f32x4* lds4 = reinterpret_cast<f32x4*>(lds);
    #pragma unroll
    for (int v = threadIdx.x; v < PPB * 49; v += BLOCK) {
        lds4[v] = in4[v];
    }
    __syncthreads();

    // ---- compute: 1568 outputs = 392 x 16B regular stores ----
    f32x4* __restrict__ out4 =
        reinterpret_cast<f32x4*>(out + (size_t)pb * 49);  // 6272 B aligned
    const int t = threadIdx.x;
    if (t < PPB * 49 / 4) {            // 392 active threads
        f32x4 r;
        #pragma unroll
        for (int q = 0; q < 4; ++q) {
            int o   = 4 * t + q;
            int p   = o / 49;          // plane within block (magic-mul)
            int rem = o - p * 49;
            int i   = rem / 7;         // output row
            int j   = rem - i * 7;     // output col
            const float* base = lds + p * 196 + i * 28 + 2 * j;
            float2 a = *reinterpret_cast<const float2*>(base);        // row 2i
            float2 b = *reinterpret_cast<const float2*>(base + 14);   // row 2i+1
            r[q] = fmaxf(fmaxf(a.x, a.y), fmaxf(b.x, b.y));
        }
        out4[t] = r;
    }
}

extern "C" void kernel_launch(void* const* d_in, const int* in_sizes, int n_in,
                              void* d_out, int out_size, void* d_ws, size_t ws_size,
                              hipStream_t stream) {
    const float* in = (const float*)d_in[0];
    float* out = (float*)d_out;
    int n_planes = out_size / 49;            // 512*256 = 131072, divisible by PPB
    int grid = n_planes / PPB;               // 4096 blocks
    ROIPooling_86466281603470_kernel<<<grid, BLOCK, 0, stream>>>(in, out);
}